// Round 3
// baseline (405.113 us; speedup 1.0000x reference)
//
#include <hip/hip_runtime.h>
#include <utility>

#define NQ 6
#define DIM 64

namespace {

// ---- compile-time ring permutation (CNOT ladder), matching _ring_perm ----
constexpr int ring_entry(int r, int i) {
    int idx = i;
    for (int w = NQ - 1; w >= 0; --w) {
        int c = w;
        int t = (w + r) % NQ;
        int cbit = (idx >> (NQ - 1 - c)) & 1;
        idx ^= cbit << (NQ - 1 - t);
    }
    return idx;
}

// Logical->physical composed map after L rings (all rings are GF(2)-linear).
// Rings in order: R1 (after layer0), R2 (after layer1), R1 (after layer2).
constexpr int Mc(int L, int i) {
    if (L == 1) return ring_entry(1, i);
    if (L == 2) return ring_entry(1, ring_entry(2, i));
    if (L == 3) return ring_entry(1, ring_entry(2, ring_entry(1, i)));
    return i;
}

constexpr int Minv(int L, int p) {
    for (int i = 0; i < DIM; ++i) if (Mc(L, i) == p) return i;
    return -1;
}

} // namespace

// ---- 1-instr VALU quad lane swap: DPP quad_perm, lane -> lane ^ HS ----
template<int HS>
__device__ __forceinline__ float qswap(float v) {
    constexpr int ctl = (HS == 1) ? 0xB1          // [1,0,3,2]
                      : (HS == 2) ? 0x4E          // [2,3,0,1]
                                  : 0x1B;         // [3,2,1,0]
    return __int_as_float(__builtin_amdgcn_mov_dpp(__float_as_int(v), ctl, 0xF, 0xF, true));
}

// ===== gate application in the fixed physical frame via composed maps =====
// 4 lanes per row: lane sub = t&3 holds physical slots p = sub*16 + l, l in [0,16).
// p bit5 (=32) <-> sub bit1; p bit4 (=16) <-> sub bit0; p bits 3..0 <-> l.
// logical i = Minv(L, p) = Minv(L,l) ^ sub0*Minv(L,16) ^ sub1*Minv(L,32) (GF(2)-linear).

template<int LY, int W, int d, int... Ls>
__device__ __forceinline__ void wire_inlane(float* sr, float* si,
        float A0r, float A0i, float B0r, float B0i,
        float A1r, float A1i, float B1r, float B1i,
        std::integer_sequence<int, Ls...>) {
    (([&] {
        if constexpr (Ls < (Ls ^ d)) {
            constexpr int la = Ls, lb = Ls ^ d;
            constexpr int ra = (Minv(LY, la) >> (5 - W)) & 1;
            constexpr int rb = (Minv(LY, lb) >> (5 - W)) & 1;
            const float cAar = ra ? A1r : A0r, cAai = ra ? A1i : A0i;
            const float cBar = ra ? B1r : B0r, cBai = ra ? B1i : B0i;
            const float cAbr = rb ? A1r : A0r, cAbi = rb ? A1i : A0i;
            const float cBbr = rb ? B1r : B0r, cBbi = rb ? B1i : B0i;
            const float mar = sr[la], mai = si[la];
            const float mbr = sr[lb], mbi = si[lb];
            sr[la] = cAar*mar - cAai*mai + cBar*mbr - cBai*mbi;
            si[la] = cAar*mai + cAai*mar + cBar*mbi + cBai*mbr;
            sr[lb] = cAbr*mbr - cAbi*mbi + cBbr*mar - cBbi*mai;
            si[lb] = cAbr*mbi + cAbi*mbr + cBbr*mai + cBbi*mar;
        }
    }()), ...);
}

template<int LY, int W, int HS, int... Ls>
__device__ __forceinline__ void wire_cross0(float* sr, float* si,
        float A0r, float A0i, float B0r, float B0i,
        float A1r, float A1i, float B1r, float B1i,
        std::integer_sequence<int, Ls...>) {
    (([&] {
        constexpr int r = (Minv(LY, Ls) >> (5 - W)) & 1;
        const float cAr = r ? A1r : A0r, cAi = r ? A1i : A0i;
        const float cBr = r ? B1r : B0r, cBi = r ? B1i : B0i;
        const float mr = sr[Ls], mi = si[Ls];
        const float tr = qswap<HS>(mr), ti = qswap<HS>(mi);  // partner lane, same l
        sr[Ls] = cAr*mr - cAi*mi + cBr*tr - cBi*ti;
        si[Ls] = cAr*mi + cAi*mr + cBr*ti + cBi*tr;
    }()), ...);
}

template<int LY, int W, int HS, int d, int... Ls>
__device__ __forceinline__ void wire_crossd(float* sr, float* si,
        float A0r, float A0i, float B0r, float B0i,
        float A1r, float A1i, float B1r, float B1i,
        std::integer_sequence<int, Ls...>) {
    (([&] {
        if constexpr (Ls < (Ls ^ d)) {
            constexpr int la = Ls, lb = Ls ^ d;
            constexpr int ra = (Minv(LY, la) >> (5 - W)) & 1;
            constexpr int rb = (Minv(LY, lb) >> (5 - W)) & 1;
            const float cAar = ra ? A1r : A0r, cAai = ra ? A1i : A0i;
            const float cBar = ra ? B1r : B0r, cBai = ra ? B1i : B0i;
            const float cAbr = rb ? A1r : A0r, cAbi = rb ? A1i : A0i;
            const float cBbr = rb ? B1r : B0r, cBbi = rb ? B1i : B0i;
            const float mar = sr[la], mai = si[la];
            const float mbr = sr[lb], mbi = si[lb];
            const float tar = qswap<HS>(mbr), tai_ = qswap<HS>(mbi); // partner of (sub,la)
            const float tbr = qswap<HS>(mar), tbi_ = qswap<HS>(mai); // partner of (sub,lb)
            sr[la] = cAar*mar - cAai*mai + cBar*tar - cBai*tai_;
            si[la] = cAar*mai + cAai*mar + cBar*tai_ + cBai*tar;
            sr[lb] = cAbr*mbr - cAbi*mbi + cBbr*tbr - cBbi*tbi_;
            si[lb] = cAbr*mbi + cAbi*mbr + cBbr*tbi_ + cBbi*tbr;
        }
    }()), ...);
}

template<int LY, int W>
__device__ __forceinline__ void wire_apply(float* sr, float* si,
        const float* __restrict__ g, int sub) {
    constexpr int D  = Mc(LY, 1 << (5 - W));   // physical pair offset (linear map)
    constexpr int HS = (D >> 4) & 3;           // cross-lane XOR within the quad
    constexpr int d  = D & 15;                 // in-lane slot XOR
    constexpr int c32 = (Minv(LY, 32) >> (5 - W)) & 1;  // role flip from sub bit1
    constexpr int c16 = (Minv(LY, 16) >> (5 - W)) & 1;  // role flip from sub bit0

    // role-hoisted coefficients: slot role = r_l(l) ^ f(sub)
    float A0r, A0i, B0r, B0i, A1r, A1i, B1r, B1i;
    if constexpr (c32 == 0 && c16 == 0) {
        A0r = g[0]; A0i = g[1]; B0r = g[2]; B0i = g[3];
        A1r = g[6]; A1i = g[7]; B1r = g[4]; B1i = g[5];
    } else {
        const bool f = ((((sub >> 1) & c32) ^ (sub & c16)) & 1) != 0;
        A0r = f ? g[6] : g[0];  A0i = f ? g[7] : g[1];
        B0r = f ? g[4] : g[2];  B0i = f ? g[5] : g[3];
        A1r = f ? g[0] : g[6];  A1i = f ? g[1] : g[7];
        B1r = f ? g[2] : g[4];  B1i = f ? g[3] : g[5];
    }
    if constexpr (HS == 0) {
        wire_inlane<LY, W, d>(sr, si, A0r, A0i, B0r, B0i, A1r, A1i, B1r, B1i,
                              std::make_integer_sequence<int, 16>{});
    } else if constexpr (d == 0) {
        wire_cross0<LY, W, HS>(sr, si, A0r, A0i, B0r, B0i, A1r, A1i, B1r, B1i,
                               std::make_integer_sequence<int, 16>{});
    } else {
        wire_crossd<LY, W, HS, d>(sr, si, A0r, A0i, B0r, B0i, A1r, A1i, B1r, B1i,
                                  std::make_integer_sequence<int, 16>{});
    }
}

template<int LY>
__device__ __forceinline__ void layer_apply(float* sr, float* si,
        const float* __restrict__ g, int sub) {
    wire_apply<LY, 0>(sr, si, g,      sub);
    wire_apply<LY, 1>(sr, si, g + 8,  sub);
    wire_apply<LY, 2>(sr, si, g + 16, sub);
    wire_apply<LY, 3>(sr, si, g + 24, sub);
    wire_apply<LY, 4>(sr, si, g + 32, sub);
    wire_apply<LY, 5>(sr, si, g + 40, sub);
}

// ---- readout: fold M3 into constexpr signs (l part) + runtime sub flips ----
template<int... Ls>
__device__ __forceinline__ void readout_impl(const float* sr, const float* si, float* q,
                                             std::integer_sequence<int, Ls...>) {
    (([&] {
        constexpr int iv = Minv(3, Ls);
        const float pb = sr[Ls]*sr[Ls] + si[Ls]*si[Ls];
        q[0] += ((iv >> 5) & 1) ? -pb : pb;
        q[1] += ((iv >> 4) & 1) ? -pb : pb;
        q[2] += ((iv >> 3) & 1) ? -pb : pb;
        q[3] += ((iv >> 2) & 1) ? -pb : pb;
        q[4] += ((iv >> 1) & 1) ? -pb : pb;
        q[5] += ( iv       & 1) ? -pb : pb;
    }()), ...);
}

// ---- per-thread gate computation (fallback path only) ----
__device__ __forceinline__ void compute_gates6(const float* __restrict__ th, float* g) {
#pragma unroll
    for (int w = 0; w < NQ; ++w) {
        const float phi = th[w*3+0], theta = th[w*3+1], omega = th[w*3+2];
        float s, c, sa, ca, sb, cb;
        __sincosf(0.5f * theta, &s, &c);
        __sincosf(0.5f * (phi + omega), &sa, &ca);
        __sincosf(0.5f * (phi - omega), &sb, &cb);
        g[w*8+0] =  ca * c;  g[w*8+1] = -sa * c;
        g[w*8+2] = -cb * s;  g[w*8+3] = -sb * s;
        g[w*8+4] =  cb * s;  g[w*8+5] = -sb * s;
        g[w*8+6] =  ca * c;  g[w*8+7] =  sa * c;
    }
}

// ---- setup: gates (18x8) + Gt[j][m] = ln_g[j]*W2[m][j] (64x6) + C1/C2 ----
// ws floats: [0,144) gates, [144,528) Gt (j*6+m), [528,534) C1, [534,540) C2+b2
__global__ void setup_kernel(const float* __restrict__ th_s, const float* __restrict__ th_t,
                             const float* __restrict__ ln_g, const float* __restrict__ ln_b,
                             const float* __restrict__ W2, const float* __restrict__ b2,
                             float* __restrict__ ws) {
    const int t = threadIdx.x;
    if (t < 18) {
        const int l = t / 6, w = t % 6;
        const float* th = (l < 2) ? (th_s + (l * 6 + w) * 3) : (th_t + w * 3);
        const float phi = th[0], theta = th[1], omega = th[2];
        float s, c, sa, ca, sb, cb;
        sincosf(0.5f * theta, &s, &c);
        sincosf(0.5f * (phi + omega), &sa, &ca);
        sincosf(0.5f * (phi - omega), &sb, &cb);
        float* g = ws + t * 8;
        g[0] =  ca * c;  g[1] = -sa * c;
        g[2] = -cb * s;  g[3] = -sb * s;
        g[4] =  cb * s;  g[5] = -sb * s;
        g[6] =  ca * c;  g[7] =  sa * c;
    }
    if (t < 384) {
        const int j = t / 6, m = t % 6;
        ws[144 + t] = ln_g[j] * W2[m * 64 + j];
    }
    if (t < 6) {
        float c1 = 0.f, c2 = 0.f;
        for (int j = 0; j < 64; ++j) {
            c1 += ln_g[j] * W2[t * 64 + j];
            c2 += ln_b[j] * W2[t * 64 + j];
        }
        ws[528 + t] = c1;
        ws[534 + t] = c2 + b2[t];
    }
}

template<bool USE_WS>
__global__ __launch_bounds__(256, 8)   // cap 64 VGPR -> 8 blocks/CU (32 waves/CU)
void qmaml_kernel(
    const float* __restrict__ x,  const float* __restrict__ W1, const float* __restrict__ b1,
    const float* __restrict__ ln_g, const float* __restrict__ ln_b,
    const float* __restrict__ W2, const float* __restrict__ b2,
    const float* __restrict__ th_s, const float* __restrict__ th_t,
    const float* __restrict__ Wc, const float* __restrict__ bc,
    const float* __restrict__ ws, float* __restrict__ out, int nrows) {

    const int t   = blockIdx.x * 256 + threadIdx.x;
    const int row = t >> 2;
    const int sub = t & 3;             // (wire0,wire1) bits of my 16-amp block
    if (row >= nrows) return;

    // ---- load MY QUARTER of the x row (K-split across the quad) ----
    float4 xv[4];
    const float4* xp = (const float4*)(x + (long)row * 64 + sub * 16);
#pragma unroll
    for (int k = 0; k < 4; ++k) xv[k] = xp[k];

    // ---- fused matvec + relu + LN-stats + folded (g*W2) projection ----
    // Each lane computes a quarter dot; the quad reassembles with two DPP
    // butterflies. All 4 lanes end with bit-identical acc (commutativity),
    // so stats/A stay lockstep-consistent across the quad.
    float A[6]  = {0.f, 0.f, 0.f, 0.f, 0.f, 0.f};
    float C1[6] = {0.f, 0.f, 0.f, 0.f, 0.f, 0.f};
    float C2[6] = {0.f, 0.f, 0.f, 0.f, 0.f, 0.f};
    float s = 0.f, s2 = 0.f;

    const float4* wbase = (const float4*)(W1 + sub * 16);
#pragma unroll 2
    for (int j = 0; j < 64; ++j) {
        const float4* wr = wbase + j * 16;
        float p0 = 0.f, p1 = 0.f;
        {
            const float4 a4 = wr[0];
            const float4 b4 = wr[1];
            const float4 c4 = wr[2];
            const float4 d4 = wr[3];
            p0 = fmaf(a4.x, xv[0].x, p0); p0 = fmaf(a4.y, xv[0].y, p0);
            p0 = fmaf(a4.z, xv[0].z, p0); p0 = fmaf(a4.w, xv[0].w, p0);
            p1 = fmaf(b4.x, xv[1].x, p1); p1 = fmaf(b4.y, xv[1].y, p1);
            p1 = fmaf(b4.z, xv[1].z, p1); p1 = fmaf(b4.w, xv[1].w, p1);
            p0 = fmaf(c4.x, xv[2].x, p0); p0 = fmaf(c4.y, xv[2].y, p0);
            p0 = fmaf(c4.z, xv[2].z, p0); p0 = fmaf(c4.w, xv[2].w, p0);
            p1 = fmaf(d4.x, xv[3].x, p1); p1 = fmaf(d4.y, xv[3].y, p1);
            p1 = fmaf(d4.z, xv[3].z, p1); p1 = fmaf(d4.w, xv[3].w, p1);
        }
        float p = p0 + p1;
        p += qswap<1>(p);                       // pairwise
        p += qswap<2>(p);                       // full quad: all lanes = total
        const float acc = fmaxf(p + b1[j], 0.f);
        s += acc; s2 += acc * acc;
        if constexpr (USE_WS) {
            const float* Gt = ws + 144 + j * 6;
#pragma unroll
            for (int m = 0; m < 6; ++m) A[m] = fmaf(acc, Gt[m], A[m]);
        } else {
            const float gj = ln_g[j], bj = ln_b[j];
#pragma unroll
            for (int m = 0; m < 6; ++m) {
                const float w2 = W2[m * 64 + j];
                const float gw = gj * w2;
                A[m]  = fmaf(acc, gw, A[m]);
                C1[m] += gw;
                C2[m] = fmaf(bj, w2, C2[m]);
            }
        }
    }

    const float mu  = s  * (1.f / 64.f);
    const float var = s2 * (1.f / 64.f) - mu * mu;
    const float inv = rsqrtf(var + 1e-5f);

    // ---- z = tanh(...), per-wire (cos, sin) ----
    float vc[6], vsn[6];
#pragma unroll
    for (int m = 0; m < 6; ++m) {
        float c1v, c2v;
        if constexpr (USE_WS) { c1v = ws[528 + m]; c2v = ws[534 + m]; }
        else                  { c1v = C1[m];       c2v = C2[m] + b2[m]; }
        const float zp = inv * (A[m] - mu * c1v) + c2v;
        const float e  = __expf(2.f * zp);
        const float z  = 1.f - 2.f / (e + 1.f);
        const float half = 1.57079632679f * z;
        vsn[m] = __sinf(half);
        vc[m]  = __cosf(half);
    }

    float gf[48];
    const float* g0;
    if constexpr (USE_WS) g0 = ws;
    else { compute_gates6(th_s, gf); g0 = gf; }

    // ---- layer-0 gates folded into per-wire product vectors ----
    float gar[6], gai[6], gbr[6], gbi[6];
#pragma unroll
    for (int w = 0; w < 6; ++w) {
        const float c = vc[w], sv = vsn[w];
        gar[w] = g0[w*8+0]*c + g0[w*8+2]*sv;
        gai[w] = g0[w*8+1]*c + g0[w*8+3]*sv;
        gbr[w] = g0[w*8+4]*c + g0[w*8+6]*sv;
        gbi[w] = g0[w*8+5]*c + g0[w*8+7]*sv;
    }

    // ---- build my 16 amps of the product state (wire0=sub>>1, wire1=sub&1) ----
    float c1r, c1i;
    {
        const float a0r = (sub & 2) ? gbr[0] : gar[0];
        const float a0i = (sub & 2) ? gbi[0] : gai[0];
        const float a1r = (sub & 1) ? gbr[1] : gar[1];
        const float a1i = (sub & 1) ? gbi[1] : gai[1];
        c1r = a0r * a1r - a0i * a1i;
        c1i = a0r * a1i + a0i * a1r;
    }
    float c2r_[2], c2i_[2];
#pragma unroll
    for (int k = 0; k < 2; ++k) {
        const float yr = k ? gbr[2] : gar[2], yi = k ? gbi[2] : gai[2];
        c2r_[k] = c1r * yr - c1i * yi;
        c2i_[k] = c1r * yi + c1i * yr;
    }
    float c3r[4], c3i[4];
#pragma unroll
    for (int k = 0; k < 4; ++k) {
        const int h = k >> 1, b = k & 1;
        const float yr = b ? gbr[3] : gar[3], yi = b ? gbi[3] : gai[3];
        c3r[k] = c2r_[h] * yr - c2i_[h] * yi;
        c3i[k] = c2r_[h] * yi + c2i_[h] * yr;
    }
    float c4r[8], c4i[8];
#pragma unroll
    for (int k = 0; k < 8; ++k) {
        const int h = k >> 1, b = k & 1;
        const float yr = b ? gbr[4] : gar[4], yi = b ? gbi[4] : gai[4];
        c4r[k] = c3r[h] * yr - c3i[h] * yi;
        c4i[k] = c3r[h] * yi + c3i[h] * yr;
    }
    float sr[16], si[16];
#pragma unroll
    for (int k = 0; k < 16; ++k) {
        const int h = k >> 1, b = k & 1;
        const float yr = b ? gbr[5] : gar[5], yi = b ? gbi[5] : gai[5];
        sr[k] = c4r[h] * yr - c4i[h] * yi;
        si[k] = c4r[h] * yi + c4i[h] * yr;
    }

    // ---- layers act through composed maps; NO physical permutations ----
    if constexpr (USE_WS) {
        layer_apply<1>(sr, si, ws + 48, sub);
        layer_apply<2>(sr, si, ws + 96, sub);
    } else {
        compute_gates6(th_s + 18, gf);
        layer_apply<1>(sr, si, gf, sub);
        compute_gates6(th_t, gf);
        layer_apply<2>(sr, si, gf, sub);
    }

    // ---- <Z_w> readout through M3 ----
    float q[6] = {0.f, 0.f, 0.f, 0.f, 0.f, 0.f};
    readout_impl(sr, si, q, std::make_integer_sequence<int, 16>{});

    constexpr int K16 = Minv(3, 16);   // sub bit0 contribution to M3^-1
    constexpr int K32 = Minv(3, 32);   // sub bit1 contribution to M3^-1
    const int s0 = sub & 1, s1 = (sub >> 1) & 1;
#pragma unroll
    for (int w = 0; w < 6; ++w) {
        const int flip = (s0 & ((K16 >> (5 - w)) & 1)) ^ (s1 & ((K32 >> (5 - w)) & 1));
        float tq = flip ? -q[w] : q[w];
        tq += qswap<1>(tq);
        tq += qswap<2>(tq);            // all lanes hold the full quad sum
        q[w] = tq;
    }

    // ---- head: out = q @ Wc^T + bc (split store across the quad) ----
    float o[5];
#pragma unroll
    for (int n = 0; n < 5; ++n) {
        float v = bc[n];
#pragma unroll
        for (int w = 0; w < 6; ++w) v = fmaf(q[w], Wc[n * 6 + w], v);
        o[n] = v;
    }
    float* orow = out + (long)row * 5;
    if (sub == 3) { orow[3] = o[3]; orow[4] = o[4]; }
    else          { orow[sub] = o[sub]; }
}

extern "C" void kernel_launch(void* const* d_in, const int* in_sizes, int n_in,
                              void* d_out, int out_size, void* d_ws, size_t ws_size,
                              hipStream_t stream) {
    const float* x   = (const float*)d_in[0];
    const float* W1  = (const float*)d_in[1];
    const float* b1  = (const float*)d_in[2];
    const float* lng = (const float*)d_in[3];
    const float* lnb = (const float*)d_in[4];
    const float* W2  = (const float*)d_in[5];
    const float* b2  = (const float*)d_in[6];
    const float* ths = (const float*)d_in[7];
    const float* tht = (const float*)d_in[8];
    const float* Wc  = (const float*)d_in[9];
    const float* bc  = (const float*)d_in[10];
    float* out = (float*)d_out;
    float* ws  = (float*)d_ws;

    const int nrows = in_sizes[0] / 64;              // 131072
    const long nthreads = (long)nrows * 4;           // 4 lanes per row
    const int grid = (int)((nthreads + 255) / 256);

    if (ws_size >= 540 * sizeof(float)) {
        setup_kernel<<<1, 384, 0, stream>>>(ths, tht, lng, lnb, W2, b2, ws);
        qmaml_kernel<true><<<grid, 256, 0, stream>>>(x, W1, b1, lng, lnb, W2, b2,
                                                     ths, tht, Wc, bc, ws, out, nrows);
    } else {
        qmaml_kernel<false><<<grid, 256, 0, stream>>>(x, W1, b1, lng, lnb, W2, b2,
                                                      ths, tht, Wc, bc, nullptr, out, nrows);
    }
}

// Round 4
// 333.744 us; speedup vs baseline: 1.2138x; 1.2138x over previous
//
#include <hip/hip_runtime.h>
#include <utility>

#define NQ 6
#define DIM 64

namespace {

// ---- compile-time ring permutation (CNOT ladder), matching _ring_perm ----
constexpr int ring_entry(int r, int i) {
    int idx = i;
    for (int w = NQ - 1; w >= 0; --w) {
        int c = w;
        int t = (w + r) % NQ;
        int cbit = (idx >> (NQ - 1 - c)) & 1;
        idx ^= cbit << (NQ - 1 - t);
    }
    return idx;
}

// Logical->physical composed map after L rings (all rings are GF(2)-linear).
// Rings in order: R1 (after layer0), R2 (after layer1), R1 (after layer2).
constexpr int Mc(int L, int i) {
    if (L == 1) return ring_entry(1, i);
    if (L == 2) return ring_entry(1, ring_entry(2, i));
    if (L == 3) return ring_entry(1, ring_entry(2, ring_entry(1, i)));
    return i;
}

constexpr int Minv(int L, int p) {
    for (int i = 0; i < DIM; ++i) if (Mc(L, i) == p) return i;
    return -1;
}

} // namespace

// ---- 1-instr VALU quad lane swap: DPP quad_perm, lane -> lane ^ HS ----
template<int HS>
__device__ __forceinline__ float qswap(float v) {
    constexpr int ctl = (HS == 1) ? 0xB1          // [1,0,3,2]
                      : (HS == 2) ? 0x4E          // [2,3,0,1]
                                  : 0x1B;         // [3,2,1,0]
    return __int_as_float(__builtin_amdgcn_mov_dpp(__float_as_int(v), ctl, 0xF, 0xF, true));
}

// ===== gate application in the fixed physical frame via composed maps =====
// 4 lanes per row: lane sub = t&3 holds physical slots p = sub*16 + l, l in [0,16).
// p bit5 (=32) <-> sub bit1; p bit4 (=16) <-> sub bit0; p bits 3..0 <-> l.
// logical i = Minv(L, p) = Minv(L,l) ^ sub0*Minv(L,16) ^ sub1*Minv(L,32) (GF(2)-linear).

template<int LY, int W, int d, int... Ls>
__device__ __forceinline__ void wire_inlane(float* sr, float* si,
        float A0r, float A0i, float B0r, float B0i,
        float A1r, float A1i, float B1r, float B1i,
        std::integer_sequence<int, Ls...>) {
    (([&] {
        if constexpr (Ls < (Ls ^ d)) {
            constexpr int la = Ls, lb = Ls ^ d;
            constexpr int ra = (Minv(LY, la) >> (5 - W)) & 1;
            constexpr int rb = (Minv(LY, lb) >> (5 - W)) & 1;
            const float cAar = ra ? A1r : A0r, cAai = ra ? A1i : A0i;
            const float cBar = ra ? B1r : B0r, cBai = ra ? B1i : B0i;
            const float cAbr = rb ? A1r : A0r, cAbi = rb ? A1i : A0i;
            const float cBbr = rb ? B1r : B0r, cBbi = rb ? B1i : B0i;
            const float mar = sr[la], mai = si[la];
            const float mbr = sr[lb], mbi = si[lb];
            sr[la] = cAar*mar - cAai*mai + cBar*mbr - cBai*mbi;
            si[la] = cAar*mai + cAai*mar + cBar*mbi + cBai*mbr;
            sr[lb] = cAbr*mbr - cAbi*mbi + cBbr*mar - cBbi*mai;
            si[lb] = cAbr*mbi + cAbi*mbr + cBbr*mai + cBbi*mar;
        }
    }()), ...);
}

template<int LY, int W, int HS, int... Ls>
__device__ __forceinline__ void wire_cross0(float* sr, float* si,
        float A0r, float A0i, float B0r, float B0i,
        float A1r, float A1i, float B1r, float B1i,
        std::integer_sequence<int, Ls...>) {
    (([&] {
        constexpr int r = (Minv(LY, Ls) >> (5 - W)) & 1;
        const float cAr = r ? A1r : A0r, cAi = r ? A1i : A0i;
        const float cBr = r ? B1r : B0r, cBi = r ? B1i : B0i;
        const float mr = sr[Ls], mi = si[Ls];
        const float tr = qswap<HS>(mr), ti = qswap<HS>(mi);  // partner lane, same l
        sr[Ls] = cAr*mr - cAi*mi + cBr*tr - cBi*ti;
        si[Ls] = cAr*mi + cAi*mr + cBr*ti + cBi*tr;
    }()), ...);
}

template<int LY, int W, int HS, int d, int... Ls>
__device__ __forceinline__ void wire_crossd(float* sr, float* si,
        float A0r, float A0i, float B0r, float B0i,
        float A1r, float A1i, float B1r, float B1i,
        std::integer_sequence<int, Ls...>) {
    (([&] {
        if constexpr (Ls < (Ls ^ d)) {
            constexpr int la = Ls, lb = Ls ^ d;
            constexpr int ra = (Minv(LY, la) >> (5 - W)) & 1;
            constexpr int rb = (Minv(LY, lb) >> (5 - W)) & 1;
            const float cAar = ra ? A1r : A0r, cAai = ra ? A1i : A0i;
            const float cBar = ra ? B1r : B0r, cBai = ra ? B1i : B0i;
            const float cAbr = rb ? A1r : A0r, cAbi = rb ? A1i : A0i;
            const float cBbr = rb ? B1r : B0r, cBbi = rb ? B1i : B0i;
            const float mar = sr[la], mai = si[la];
            const float mbr = sr[lb], mbi = si[lb];
            const float tar = qswap<HS>(mbr), tai_ = qswap<HS>(mbi); // partner of (sub,la)
            const float tbr = qswap<HS>(mar), tbi_ = qswap<HS>(mai); // partner of (sub,lb)
            sr[la] = cAar*mar - cAai*mai + cBar*tar - cBai*tai_;
            si[la] = cAar*mai + cAai*mar + cBar*tai_ + cBai*tar;
            sr[lb] = cAbr*mbr - cAbi*mbi + cBbr*tbr - cBbi*tbi_;
            si[lb] = cAbr*mbi + cAbi*mbr + cBbr*tbi_ + cBbi*tbr;
        }
    }()), ...);
}

template<int LY, int W>
__device__ __forceinline__ void wire_apply(float* sr, float* si,
        const float* __restrict__ g, int sub) {
    constexpr int D  = Mc(LY, 1 << (5 - W));   // physical pair offset (linear map)
    constexpr int HS = (D >> 4) & 3;           // cross-lane XOR within the quad
    constexpr int d  = D & 15;                 // in-lane slot XOR
    constexpr int c32 = (Minv(LY, 32) >> (5 - W)) & 1;  // role flip from sub bit1
    constexpr int c16 = (Minv(LY, 16) >> (5 - W)) & 1;  // role flip from sub bit0

    // role-hoisted coefficients: slot role = r_l(l) ^ f(sub)
    float A0r, A0i, B0r, B0i, A1r, A1i, B1r, B1i;
    if constexpr (c32 == 0 && c16 == 0) {
        A0r = g[0]; A0i = g[1]; B0r = g[2]; B0i = g[3];
        A1r = g[6]; A1i = g[7]; B1r = g[4]; B1i = g[5];
    } else {
        const bool f = ((((sub >> 1) & c32) ^ (sub & c16)) & 1) != 0;
        A0r = f ? g[6] : g[0];  A0i = f ? g[7] : g[1];
        B0r = f ? g[4] : g[2];  B0i = f ? g[5] : g[3];
        A1r = f ? g[0] : g[6];  A1i = f ? g[1] : g[7];
        B1r = f ? g[2] : g[4];  B1i = f ? g[3] : g[5];
    }
    if constexpr (HS == 0) {
        wire_inlane<LY, W, d>(sr, si, A0r, A0i, B0r, B0i, A1r, A1i, B1r, B1i,
                              std::make_integer_sequence<int, 16>{});
    } else if constexpr (d == 0) {
        wire_cross0<LY, W, HS>(sr, si, A0r, A0i, B0r, B0i, A1r, A1i, B1r, B1i,
                               std::make_integer_sequence<int, 16>{});
    } else {
        wire_crossd<LY, W, HS, d>(sr, si, A0r, A0i, B0r, B0i, A1r, A1i, B1r, B1i,
                                  std::make_integer_sequence<int, 16>{});
    }
}

template<int LY>
__device__ __forceinline__ void layer_apply(float* sr, float* si,
        const float* __restrict__ g, int sub) {
    wire_apply<LY, 0>(sr, si, g,      sub);
    wire_apply<LY, 1>(sr, si, g + 8,  sub);
    wire_apply<LY, 2>(sr, si, g + 16, sub);
    wire_apply<LY, 3>(sr, si, g + 24, sub);
    wire_apply<LY, 4>(sr, si, g + 32, sub);
    wire_apply<LY, 5>(sr, si, g + 40, sub);
}

// ---- readout: fold M3 into constexpr signs (l part) + runtime sub flips ----
template<int... Ls>
__device__ __forceinline__ void readout_impl(const float* sr, const float* si, float* q,
                                             std::integer_sequence<int, Ls...>) {
    (([&] {
        constexpr int iv = Minv(3, Ls);
        const float pb = sr[Ls]*sr[Ls] + si[Ls]*si[Ls];
        q[0] += ((iv >> 5) & 1) ? -pb : pb;
        q[1] += ((iv >> 4) & 1) ? -pb : pb;
        q[2] += ((iv >> 3) & 1) ? -pb : pb;
        q[3] += ((iv >> 2) & 1) ? -pb : pb;
        q[4] += ((iv >> 1) & 1) ? -pb : pb;
        q[5] += ( iv       & 1) ? -pb : pb;
    }()), ...);
}

// ---- per-thread gate computation (fallback path only) ----
__device__ __forceinline__ void compute_gates6(const float* __restrict__ th, float* g) {
#pragma unroll
    for (int w = 0; w < NQ; ++w) {
        const float phi = th[w*3+0], theta = th[w*3+1], omega = th[w*3+2];
        float s, c, sa, ca, sb, cb;
        __sincosf(0.5f * theta, &s, &c);
        __sincosf(0.5f * (phi + omega), &sa, &ca);
        __sincosf(0.5f * (phi - omega), &sb, &cb);
        g[w*8+0] =  ca * c;  g[w*8+1] = -sa * c;
        g[w*8+2] = -cb * s;  g[w*8+3] = -sb * s;
        g[w*8+4] =  cb * s;  g[w*8+5] = -sb * s;
        g[w*8+6] =  ca * c;  g[w*8+7] =  sa * c;
    }
}

// ---- setup: gates (18x8) + Gt[j][m] = ln_g[j]*W2[m][j] (64x6) + C1/C2 ----
// ws floats: [0,144) gates, [144,528) Gt (j*6+m), [528,534) C1, [534,540) C2+b2
__global__ void setup_kernel(const float* __restrict__ th_s, const float* __restrict__ th_t,
                             const float* __restrict__ ln_g, const float* __restrict__ ln_b,
                             const float* __restrict__ W2, const float* __restrict__ b2,
                             float* __restrict__ ws) {
    const int t = threadIdx.x;
    if (t < 18) {
        const int l = t / 6, w = t % 6;
        const float* th = (l < 2) ? (th_s + (l * 6 + w) * 3) : (th_t + w * 3);
        const float phi = th[0], theta = th[1], omega = th[2];
        float s, c, sa, ca, sb, cb;
        sincosf(0.5f * theta, &s, &c);
        sincosf(0.5f * (phi + omega), &sa, &ca);
        sincosf(0.5f * (phi - omega), &sb, &cb);
        float* g = ws + t * 8;
        g[0] =  ca * c;  g[1] = -sa * c;
        g[2] = -cb * s;  g[3] = -sb * s;
        g[4] =  cb * s;  g[5] = -sb * s;
        g[6] =  ca * c;  g[7] =  sa * c;
    }
    if (t < 384) {
        const int j = t / 6, m = t % 6;
        ws[144 + t] = ln_g[j] * W2[m * 64 + j];
    }
    if (t < 6) {
        float c1 = 0.f, c2 = 0.f;
        for (int j = 0; j < 64; ++j) {
            c1 += ln_g[j] * W2[t * 64 + j];
            c2 += ln_b[j] * W2[t * 64 + j];
        }
        ws[528 + t] = c1;
        ws[534 + t] = c2 + b2[t];
    }
}

template<bool USE_WS>
__global__ __launch_bounds__(256, 6)   // 85-VGPR cap -> 6 blocks/CU (24 waves/CU), no spill
void qmaml_kernel(
    const float* __restrict__ x,  const float* __restrict__ W1, const float* __restrict__ b1,
    const float* __restrict__ ln_g, const float* __restrict__ ln_b,
    const float* __restrict__ W2, const float* __restrict__ b2,
    const float* __restrict__ th_s, const float* __restrict__ th_t,
    const float* __restrict__ Wc, const float* __restrict__ bc,
    const float* __restrict__ ws, float* __restrict__ out, int nrows) {

    const int t   = blockIdx.x * 256 + threadIdx.x;
    const int row = t >> 2;
    const int sub = t & 3;             // (wire0,wire1) bits of my 16-amp block
    if (row >= nrows) return;

    // ---- load MY QUARTER of the x row (K-split across the quad) ----
    float4 xv[4];
    const float4* xp = (const float4*)(x + (long)row * 64 + sub * 16);
#pragma unroll
    for (int k = 0; k < 4; ++k) xv[k] = xp[k];

    // ---- fused matvec + relu + LN-stats + folded (g*W2) projection ----
    // Each lane computes a quarter dot; the quad reassembles with two DPP
    // butterflies. All 4 lanes end with bit-identical acc (commutativity),
    // so stats/A stay lockstep-consistent across the quad.
    float A[6]  = {0.f, 0.f, 0.f, 0.f, 0.f, 0.f};
    float C1[6] = {0.f, 0.f, 0.f, 0.f, 0.f, 0.f};
    float C2[6] = {0.f, 0.f, 0.f, 0.f, 0.f, 0.f};
    float s = 0.f, s2 = 0.f;

    const float4* wbase = (const float4*)(W1 + sub * 16);
#pragma unroll 2
    for (int j = 0; j < 64; ++j) {
        const float4* wr = wbase + j * 16;
        float p0 = 0.f, p1 = 0.f;
        {
            const float4 a4 = wr[0];
            const float4 b4 = wr[1];
            const float4 c4 = wr[2];
            const float4 d4 = wr[3];
            p0 = fmaf(a4.x, xv[0].x, p0); p0 = fmaf(a4.y, xv[0].y, p0);
            p0 = fmaf(a4.z, xv[0].z, p0); p0 = fmaf(a4.w, xv[0].w, p0);
            p1 = fmaf(b4.x, xv[1].x, p1); p1 = fmaf(b4.y, xv[1].y, p1);
            p1 = fmaf(b4.z, xv[1].z, p1); p1 = fmaf(b4.w, xv[1].w, p1);
            p0 = fmaf(c4.x, xv[2].x, p0); p0 = fmaf(c4.y, xv[2].y, p0);
            p0 = fmaf(c4.z, xv[2].z, p0); p0 = fmaf(c4.w, xv[2].w, p0);
            p1 = fmaf(d4.x, xv[3].x, p1); p1 = fmaf(d4.y, xv[3].y, p1);
            p1 = fmaf(d4.z, xv[3].z, p1); p1 = fmaf(d4.w, xv[3].w, p1);
        }
        float p = p0 + p1;
        p += qswap<1>(p);                       // pairwise
        p += qswap<2>(p);                       // full quad: all lanes = total
        const float acc = fmaxf(p + b1[j], 0.f);
        s += acc; s2 += acc * acc;
        if constexpr (USE_WS) {
            const float* Gt = ws + 144 + j * 6;
#pragma unroll
            for (int m = 0; m < 6; ++m) A[m] = fmaf(acc, Gt[m], A[m]);
        } else {
            const float gj = ln_g[j], bj = ln_b[j];
#pragma unroll
            for (int m = 0; m < 6; ++m) {
                const float w2 = W2[m * 64 + j];
                const float gw = gj * w2;
                A[m]  = fmaf(acc, gw, A[m]);
                C1[m] += gw;
                C2[m] = fmaf(bj, w2, C2[m]);
            }
        }
    }

    const float mu  = s  * (1.f / 64.f);
    const float var = s2 * (1.f / 64.f) - mu * mu;
    const float inv = rsqrtf(var + 1e-5f);

    // ---- z = tanh(...), per-wire (cos, sin) ----
    float vc[6], vsn[6];
#pragma unroll
    for (int m = 0; m < 6; ++m) {
        float c1v, c2v;
        if constexpr (USE_WS) { c1v = ws[528 + m]; c2v = ws[534 + m]; }
        else                  { c1v = C1[m];       c2v = C2[m] + b2[m]; }
        const float zp = inv * (A[m] - mu * c1v) + c2v;
        const float e  = __expf(2.f * zp);
        const float z  = 1.f - 2.f / (e + 1.f);
        const float half = 1.57079632679f * z;
        vsn[m] = __sinf(half);
        vc[m]  = __cosf(half);
    }

    float gf[48];
    const float* g0;
    if constexpr (USE_WS) g0 = ws;
    else { compute_gates6(th_s, gf); g0 = gf; }

    // ---- layer-0 gates folded into per-wire product vectors ----
    float gar[6], gai[6], gbr[6], gbi[6];
#pragma unroll
    for (int w = 0; w < 6; ++w) {
        const float c = vc[w], sv = vsn[w];
        gar[w] = g0[w*8+0]*c + g0[w*8+2]*sv;
        gai[w] = g0[w*8+1]*c + g0[w*8+3]*sv;
        gbr[w] = g0[w*8+4]*c + g0[w*8+6]*sv;
        gbi[w] = g0[w*8+5]*c + g0[w*8+7]*sv;
    }

    // ---- build my 16 amps IN PLACE (wire0=sub>>1, wire1=sub&1 via c1) ----
    // Backward in-place doubling: write k descending reads k>>1 <= k, so
    // old level values are consumed before being overwritten. No c2/c3/c4
    // intermediate arrays -> ~28 fewer live VGPRs at peak.
    float sr[16], si[16];
    {
        const float a0r = (sub & 2) ? gbr[0] : gar[0];
        const float a0i = (sub & 2) ? gbi[0] : gai[0];
        const float a1r = (sub & 1) ? gbr[1] : gar[1];
        const float a1i = (sub & 1) ? gbi[1] : gai[1];
        const float c1r = a0r * a1r - a0i * a1i;
        const float c1i = a0r * a1i + a0i * a1r;
        sr[0] = c1r * gar[2] - c1i * gai[2];
        si[0] = c1r * gai[2] + c1i * gar[2];
        sr[1] = c1r * gbr[2] - c1i * gbi[2];
        si[1] = c1r * gbi[2] + c1i * gbr[2];
    }
#pragma unroll
    for (int k = 3; k >= 0; --k) {          // wire3: 2 -> 4
        const float yr = (k & 1) ? gbr[3] : gar[3];
        const float yi = (k & 1) ? gbi[3] : gai[3];
        const float hr = sr[k >> 1], hi = si[k >> 1];
        sr[k] = hr * yr - hi * yi;
        si[k] = hr * yi + hi * yr;
    }
#pragma unroll
    for (int k = 7; k >= 0; --k) {          // wire4: 4 -> 8
        const float yr = (k & 1) ? gbr[4] : gar[4];
        const float yi = (k & 1) ? gbi[4] : gai[4];
        const float hr = sr[k >> 1], hi = si[k >> 1];
        sr[k] = hr * yr - hi * yi;
        si[k] = hr * yi + hi * yr;
    }
#pragma unroll
    for (int k = 15; k >= 0; --k) {         // wire5: 8 -> 16
        const float yr = (k & 1) ? gbr[5] : gar[5];
        const float yi = (k & 1) ? gbi[5] : gai[5];
        const float hr = sr[k >> 1], hi = si[k >> 1];
        sr[k] = hr * yr - hi * yi;
        si[k] = hr * yi + hi * yr;
    }

    // ---- layers act through composed maps; NO physical permutations ----
    if constexpr (USE_WS) {
        layer_apply<1>(sr, si, ws + 48, sub);
        layer_apply<2>(sr, si, ws + 96, sub);
    } else {
        compute_gates6(th_s + 18, gf);
        layer_apply<1>(sr, si, gf, sub);
        compute_gates6(th_t, gf);
        layer_apply<2>(sr, si, gf, sub);
    }

    // ---- <Z_w> readout through M3 ----
    float q[6] = {0.f, 0.f, 0.f, 0.f, 0.f, 0.f};
    readout_impl(sr, si, q, std::make_integer_sequence<int, 16>{});

    constexpr int K16 = Minv(3, 16);   // sub bit0 contribution to M3^-1
    constexpr int K32 = Minv(3, 32);   // sub bit1 contribution to M3^-1
    const int s0 = sub & 1, s1 = (sub >> 1) & 1;
#pragma unroll
    for (int w = 0; w < 6; ++w) {
        const int flip = (s0 & ((K16 >> (5 - w)) & 1)) ^ (s1 & ((K32 >> (5 - w)) & 1));
        float tq = flip ? -q[w] : q[w];
        tq += qswap<1>(tq);
        tq += qswap<2>(tq);            // all lanes hold the full quad sum
        q[w] = tq;
    }

    // ---- head: out = q @ Wc^T + bc (split store across the quad) ----
    float o[5];
#pragma unroll
    for (int n = 0; n < 5; ++n) {
        float v = bc[n];
#pragma unroll
        for (int w = 0; w < 6; ++w) v = fmaf(q[w], Wc[n * 6 + w], v);
        o[n] = v;
    }
    float* orow = out + (long)row * 5;
    if (sub == 3) { orow[3] = o[3]; orow[4] = o[4]; }
    else          { orow[sub] = o[sub]; }
}

extern "C" void kernel_launch(void* const* d_in, const int* in_sizes, int n_in,
                              void* d_out, int out_size, void* d_ws, size_t ws_size,
                              hipStream_t stream) {
    const float* x   = (const float*)d_in[0];
    const float* W1  = (const float*)d_in[1];
    const float* b1  = (const float*)d_in[2];
    const float* lng = (const float*)d_in[3];
    const float* lnb = (const float*)d_in[4];
    const float* W2  = (const float*)d_in[5];
    const float* b2  = (const float*)d_in[6];
    const float* ths = (const float*)d_in[7];
    const float* tht = (const float*)d_in[8];
    const float* Wc  = (const float*)d_in[9];
    const float* bc  = (const float*)d_in[10];
    float* out = (float*)d_out;
    float* ws  = (float*)d_ws;

    const int nrows = in_sizes[0] / 64;              // 131072
    const long nthreads = (long)nrows * 4;           // 4 lanes per row
    const int grid = (int)((nthreads + 255) / 256);

    if (ws_size >= 540 * sizeof(float)) {
        setup_kernel<<<1, 384, 0, stream>>>(ths, tht, lng, lnb, W2, b2, ws);
        qmaml_kernel<true><<<grid, 256, 0, stream>>>(x, W1, b1, lng, lnb, W2, b2,
                                                     ths, tht, Wc, bc, ws, out, nrows);
    } else {
        qmaml_kernel<false><<<grid, 256, 0, stream>>>(x, W1, b1, lng, lnb, W2, b2,
                                                      ths, tht, Wc, bc, nullptr, out, nrows);
    }
}